// Round 11
// baseline (295.118 us; speedup 1.0000x reference)
//
#include <hip/hip_runtime.h>
#include <math.h>

#define D_X      1024
#define D_TEXT   768
#define FDIM     1792
#define BATCH    256
#define M_EXP    16
#define HW_TOT   1024   // 32*32

// Output layout (flat f32): gates[4096] | moe_loss[1] | probs[4096] | top_idx[512]
#define OUT_GATES 0
#define OUT_LOSS  4096
#define OUT_PROBS 4097
#define OUT_IDX   8193

#define NBLK_DGEMM 224
#define NBLK_POOL  (BATCH * D_X / 4)   // 65536

// ---------------------------------------------------------------------------
// Kernel 1 (verbatim R5/R9 champion):
//   blocks [0, 224):      deg-GEMM  pact2 = degraded @ W[1024:, :]
//   blocks [224, 65760):  one-shot mean-pool, one wave per (b,c) row
// ---------------------------------------------------------------------------
__global__ __launch_bounds__(256) void pool_deggemm_kernel(const float* __restrict__ x,
                                                           const float* __restrict__ deg,
                                                           const float* __restrict__ W,
                                                           float* __restrict__ fused,
                                                           float* __restrict__ pact2) {
    __shared__ float As1[32][33];   // deg tile, transposed [k][m]
    __shared__ float Ws1[32][64];   // W tile [k][n]

    const int bid = blockIdx.x;
    const int tid = threadIdx.x;

    if (bid >= NBLK_DGEMM) {
        // ---- pool path: one wave per (b,c) row of 1024 contiguous floats ----
        const int gtid = (bid - NBLK_DGEMM) * 256 + tid;
        const int row  = gtid >> 6;            // 0 .. 262143
        const int lane = gtid & 63;
        const float4* xr = reinterpret_cast<const float4*>(x + (size_t)row * HW_TOT);
        float s = 0.0f;
#pragma unroll
        for (int k = 0; k < 4; ++k) {
            float4 v = xr[k * 64 + lane];
            s += v.x + v.y + v.z + v.w;
        }
#pragma unroll
        for (int off = 32; off > 0; off >>= 1) s += __shfl_xor(s, off, 64);
        if (lane == 0) fused[row] = s * (1.0f / 1024.0f);   // fused dense (256,1024)
        return;
    }

    // ---- deg-GEMM path: 32m x 64n tile, BK=32, 24 iters ----
    const int mb = bid / 28;
    const int nb = bid % 28;
    const int m0 = mb * 32;
    const int n0 = nb * 64;

    const int tx = tid & 15;        // n-groups of 4
    const int ty = tid >> 4;        // m-groups of 2

    const int ar  = tid >> 3;       // A row 0..31
    const int ak4 = (tid & 7) * 4;  // A k-col
    const int wk  = tid >> 4;       // W k-row (+16 for second)
    const int wc4 = (tid & 15) * 4; // W n-col

    float acc[2][4] = {};

    for (int k0 = 0; k0 < D_TEXT; k0 += 32) {
        __syncthreads();
        {
            const float4 a = *reinterpret_cast<const float4*>(
                deg + (size_t)(m0 + ar) * D_TEXT + k0 + ak4);
            As1[ak4 + 0][ar] = a.x; As1[ak4 + 1][ar] = a.y;
            As1[ak4 + 2][ar] = a.z; As1[ak4 + 3][ar] = a.w;
            *reinterpret_cast<float4*>(&Ws1[wk][wc4]) =
                *reinterpret_cast<const float4*>(W + (size_t)(D_X + k0 + wk) * FDIM + n0 + wc4);
            *reinterpret_cast<float4*>(&Ws1[wk + 16][wc4]) =
                *reinterpret_cast<const float4*>(W + (size_t)(D_X + k0 + wk + 16) * FDIM + n0 + wc4);
        }
        __syncthreads();
#pragma unroll
        for (int kk = 0; kk < 32; ++kk) {
            const float2 a = *reinterpret_cast<const float2*>(&As1[kk][ty * 2]);
            const float4 w = *reinterpret_cast<const float4*>(&Ws1[kk][tx * 4]);
            acc[0][0] = fmaf(a.x, w.x, acc[0][0]);
            acc[0][1] = fmaf(a.x, w.y, acc[0][1]);
            acc[0][2] = fmaf(a.x, w.z, acc[0][2]);
            acc[0][3] = fmaf(a.x, w.w, acc[0][3]);
            acc[1][0] = fmaf(a.y, w.x, acc[1][0]);
            acc[1][1] = fmaf(a.y, w.y, acc[1][1]);
            acc[1][2] = fmaf(a.y, w.z, acc[1][2]);
            acc[1][3] = fmaf(a.y, w.w, acc[1][3]);
        }
    }

#pragma unroll
    for (int i = 0; i < 2; ++i) {
        float4 v;
        v.x = acc[i][0]; v.y = acc[i][1]; v.z = acc[i][2]; v.w = acc[i][3];
        *reinterpret_cast<float4*>(pact2 + (size_t)(m0 + ty * 2 + i) * FDIM + n0 + tx * 4) = v;
    }
}

// ---------------------------------------------------------------------------
// Kernel 2: main GEMM K-split over 2 blocks per tile (grid 8x28x2) -> 2/CU.
// Each block: 8 BK=64 tiles (R5-proven dbuf inner loop), partial -> pactz[z].
// Second-arriving block per tile (ACQ_REL counter, no polling) does:
// pactz[0]+pactz[1]+pact2+bias (fixed order) -> GELU -> gate partials.
// Global last-of-224 winners does finalize (R9-proven).
// ---------------------------------------------------------------------------
#define BM 32
#define BN 64
#define BK 64
#define KHALF 512
#define NITER (KHALF / BK)   // 8
#define KDIM D_X

// smem: As[2][64][33] @0 (4224 f), Ws[2][64][64] @4224 (8192 f) = 12416 f
// winner overlay: actS[32][65] @0 (2080 f), wgs[64][16] @2080 (1024 f)
#define AS(buf, k, m) smem[(buf) * 2112 + (k) * 33 + (m)]
#define WS(buf, k, n) smem[4224 + (buf) * 4096 + (k) * 64 + (n)]
#define ACTS(m, n)    smem[(m) * 65 + (n)]
#define WGS(n, e)     smem[2080 + (n) * M_EXP + (e)]

#define LOADA(k0)                                                                            \
    pa0 = *reinterpret_cast<const float4*>(A + (size_t)(m0 + ar) * KDIM + (k0) + ak4);       \
    pa1 = *reinterpret_cast<const float4*>(A + (size_t)(m0 + ar + 16) * KDIM + (k0) + ak4);

#define LOADW(k0)                                                                            \
    pw0 = *reinterpret_cast<const float4*>(W + (size_t)((k0) + wr0) * FDIM + n0 + wc4);      \
    pw1 = *reinterpret_cast<const float4*>(W + (size_t)((k0) + wr0 + 16) * FDIM + n0 + wc4); \
    pw2 = *reinterpret_cast<const float4*>(W + (size_t)((k0) + wr0 + 32) * FDIM + n0 + wc4); \
    pw3 = *reinterpret_cast<const float4*>(W + (size_t)((k0) + wr0 + 48) * FDIM + n0 + wc4);

#define STOREA(buf)                                                                          \
    AS(buf, ak4 + 0, ar) = pa0.x; AS(buf, ak4 + 1, ar) = pa0.y;                              \
    AS(buf, ak4 + 2, ar) = pa0.z; AS(buf, ak4 + 3, ar) = pa0.w;                              \
    AS(buf, ak4 + 0, ar + 16) = pa1.x; AS(buf, ak4 + 1, ar + 16) = pa1.y;                    \
    AS(buf, ak4 + 2, ar + 16) = pa1.z; AS(buf, ak4 + 3, ar + 16) = pa1.w;

#define STOREW(buf)                                                                          \
    *reinterpret_cast<float4*>(&WS(buf, wr0, wc4))      = pw0;                               \
    *reinterpret_cast<float4*>(&WS(buf, wr0 + 16, wc4)) = pw1;                               \
    *reinterpret_cast<float4*>(&WS(buf, wr0 + 32, wc4)) = pw2;                               \
    *reinterpret_cast<float4*>(&WS(buf, wr0 + 48, wc4)) = pw3;

__global__ __launch_bounds__(256) void gemm_gate_kernel(const float* __restrict__ A,
                                                        const float* __restrict__ W,
                                                        const float* __restrict__ pact2,
                                                        const float* __restrict__ bias,
                                                        const float* __restrict__ wg,
                                                        float* __restrict__ pactz,
                                                        float* __restrict__ part,
                                                        int* __restrict__ tilectr,
                                                        int* __restrict__ done,
                                                        float* __restrict__ out) {
    __shared__ float smem[12416];
    __shared__ int isL;

    const int tid = threadIdx.x;
    const int m0 = blockIdx.x * BM;
    const int n0 = blockIdx.y * BN;
    const int z  = blockIdx.z;
    const int kz = z * KHALF;

    const int tx = tid & 15;
    const int ty = tid >> 4;
    const int ar  = tid >> 4;             // A rows ar, ar+16
    const int ak4 = (tid & 15) * 4;
    const int wr0 = tid >> 4;             // W k-rows wr0,+16,+32,+48
    const int wc4 = (tid & 15) * 4;

    float4 pa0, pa1, pw0, pw1, pw2, pw3;

    LOADA(kz); LOADW(kz);
    STOREA(0); STOREW(0);
    LOADA(kz + BK); LOADW(kz + BK);
    __syncthreads();

    float acc[2][4] = {};
    int cur = 0;

    for (int t = 0; t < NITER; ++t) {
#pragma unroll
        for (int kk = 0; kk < BK; ++kk) {
            const float2 a = *reinterpret_cast<const float2*>(&AS(cur, kk, ty * 2));
            const float4 w = *reinterpret_cast<const float4*>(&WS(cur, kk, tx * 4));
            acc[0][0] = fmaf(a.x, w.x, acc[0][0]);
            acc[0][1] = fmaf(a.x, w.y, acc[0][1]);
            acc[0][2] = fmaf(a.x, w.z, acc[0][2]);
            acc[0][3] = fmaf(a.x, w.w, acc[0][3]);
            acc[1][0] = fmaf(a.y, w.x, acc[1][0]);
            acc[1][1] = fmaf(a.y, w.y, acc[1][1]);
            acc[1][2] = fmaf(a.y, w.z, acc[1][2]);
            acc[1][3] = fmaf(a.y, w.w, acc[1][3]);
        }
        if (t < NITER - 1) {
            const int nxt = cur ^ 1;
            STOREA(nxt); STOREW(nxt);
            if (t < NITER - 2) {
                const int k0 = kz + (t + 2) * BK;
                LOADA(k0); LOADW(k0);
            }
            __syncthreads();
            cur = nxt;
        }
    }

    // write K-half partial
#pragma unroll
    for (int i = 0; i < 2; ++i) {
        float4 v;
        v.x = acc[i][0]; v.y = acc[i][1]; v.z = acc[i][2]; v.w = acc[i][3];
        *reinterpret_cast<float4*>(
            pactz + ((size_t)z * BATCH + m0 + ty * 2 + i) * FDIM + n0 + tx * 4) = v;
    }

    // ---- second-arriver wins the tile epilogue (no polling) ----
    __threadfence();
    __syncthreads();
    if (tid == 0) {
        const int prev = __hip_atomic_fetch_add(&tilectr[blockIdx.x * 28 + blockIdx.y], 1,
                                                __ATOMIC_ACQ_REL, __HIP_MEMORY_SCOPE_AGENT);
        isL = (prev == 1);
    }
    __syncthreads();
    if (!isL) return;

    // winner: fixed-order sum z0 + z1 + pact2 + bias -> GELU -> actS (smem reused)
    {
        const int m  = tid >> 3;             // 0..31
        const int n8 = (tid & 7) * 8;        // 0..56
        const size_t rowoff = (size_t)(m0 + m) * FDIM + n0 + n8;
        float vv[8];
        {
            const float4 q0 = *reinterpret_cast<const float4*>(pactz + rowoff);
            const float4 q1 = *reinterpret_cast<const float4*>(pactz + rowoff + 4);
            const float4 r0 = *reinterpret_cast<const float4*>(
                pactz + (size_t)BATCH * FDIM + rowoff);
            const float4 r1 = *reinterpret_cast<const float4*>(
                pactz + (size_t)BATCH * FDIM + rowoff + 4);
            const float4 p0 = *reinterpret_cast<const float4*>(pact2 + rowoff);
            const float4 p1 = *reinterpret_cast<const float4*>(pact2 + rowoff + 4);
            const float4 b0 = *reinterpret_cast<const float4*>(bias + n0 + n8);
            const float4 b1 = *reinterpret_cast<const float4*>(bias + n0 + n8 + 4);
            vv[0] = (q0.x + r0.x) + p0.x + b0.x; vv[1] = (q0.y + r0.y) + p0.y + b0.y;
            vv[2] = (q0.z + r0.z) + p0.z + b0.z; vv[3] = (q0.w + r0.w) + p0.w + b0.w;
            vv[4] = (q1.x + r1.x) + p1.x + b1.x; vv[5] = (q1.y + r1.y) + p1.y + b1.y;
            vv[6] = (q1.z + r1.z) + p1.z + b1.z; vv[7] = (q1.w + r1.w) + p1.w + b1.w;
        }
        __syncthreads();   // all GEMM smem reads done before overlay write
#pragma unroll
        for (int j = 0; j < 8; ++j)
            ACTS(m, n8 + j) = vv[j] * 0.5f * (1.0f + erff(vv[j] * 0.70710678118654752440f));
    }
    {
        const int r  = tid >> 2;
        const int c4 = (tid & 3) * 4;
        *reinterpret_cast<float4*>(&WGS(r, c4)) =
            *reinterpret_cast<const float4*>(wg + (size_t)(n0 + r) * M_EXP + c4);
    }
    __syncthreads();

    // gate partials: 32 rows x 16 experts, 2 per thread
    const int pm = tid >> 3;
    const int pe = (tid & 7) * 2;
    float s0 = 0.0f, s1 = 0.0f;
#pragma unroll
    for (int n = 0; n < BN; ++n) {
        const float a = ACTS(pm, n);
        s0 = fmaf(a, WGS(n, pe), s0);
        s1 = fmaf(a, WGS(n, pe + 1), s1);
    }
    float* pr = part + ((size_t)blockIdx.y * BATCH + m0 + pm) * M_EXP + pe;
    pr[0] = s0;
    pr[1] = s1;

    // ---- global last-of-224-winners finalize (R9-proven) ----
    __threadfence();
    __syncthreads();
    if (tid == 0) {
        const int prev = __hip_atomic_fetch_add(done, 1, __ATOMIC_ACQ_REL,
                                                __HIP_MEMORY_SCOPE_AGENT);
        isL = (prev == 8 * 28 - 1);
    }
    __syncthreads();
    if (!isL) return;

    {
        const int b = tid;    // 256 threads = 256 rows
        float l[M_EXP];
#pragma unroll
        for (int mm = 0; mm < M_EXP; ++mm) l[mm] = 0.0f;
        for (int nb2 = 0; nb2 < FDIM / BN; ++nb2) {
            const float4* prr = reinterpret_cast<const float4*>(
                part + ((size_t)nb2 * BATCH + b) * M_EXP);
#pragma unroll
            for (int q = 0; q < 4; ++q) {
                const float4 v = prr[q];
                l[q * 4 + 0] += v.x;
                l[q * 4 + 1] += v.y;
                l[q * 4 + 2] += v.z;
                l[q * 4 + 3] += v.w;
            }
        }
        float mx = l[0];
#pragma unroll
        for (int mm = 1; mm < M_EXP; ++mm) mx = fmaxf(mx, l[mm]);
        float e[M_EXP], s = 0.0f;
#pragma unroll
        for (int mm = 0; mm < M_EXP; ++mm) { e[mm] = expf(l[mm] - mx); s += e[mm]; }
        const float inv = 1.0f / s;
#pragma unroll
        for (int mm = 0; mm < M_EXP; ++mm) out[OUT_PROBS + b * M_EXP + mm] = e[mm] * inv;

        int i0 = 0; float v0 = l[0];
#pragma unroll
        for (int mm = 1; mm < M_EXP; ++mm) if (l[mm] > v0) { v0 = l[mm]; i0 = mm; }
        int i1 = -1; float v1 = -INFINITY;
#pragma unroll
        for (int mm = 0; mm < M_EXP; ++mm) if (mm != i0 && l[mm] > v1) { v1 = l[mm]; i1 = mm; }

        const float t = expf(v1 - v0);
        const float g0 = 1.0f / (1.0f + t);
        const float g1 = t * g0;
#pragma unroll
        for (int mm = 0; mm < M_EXP; ++mm) out[OUT_GATES + b * M_EXP + mm] = 0.0f;
        out[OUT_GATES + b * M_EXP + i0] = g0;
        out[OUT_GATES + b * M_EXP + i1] = g1;
        out[OUT_IDX + b * 2 + 0] = (float)i0;
        out[OUT_IDX + b * 2 + 1] = (float)i1;
        if (b == 0) out[OUT_LOSS] = 0.0f;
    }
}

// ---------------------------------------------------------------------------
extern "C" void kernel_launch(void* const* d_in, const int* in_sizes, int n_in,
                              void* d_out, int out_size, void* d_ws, size_t ws_size,
                              hipStream_t stream) {
    const float* x        = (const float*)d_in[0];
    const float* degraded = (const float*)d_in[1];
    const float* w_fusion = (const float*)d_in[2];
    const float* b_fusion = (const float*)d_in[3];
    const float* w_gate   = (const float*)d_in[4];
    float* out = (float*)d_out;

    float* fused = (float*)d_ws;                          // 256*1024 f32
    float* pact2 = fused + (size_t)BATCH * D_X;           // 256*1792 f32
    float* pactz = pact2 + (size_t)BATCH * FDIM;          // 2*256*1792 f32
    float* part  = pactz + (size_t)2 * BATCH * FDIM;      // 28*256*16 f32
    int*   ctrs  = (int*)(part + (size_t)28 * BATCH * M_EXP);  // tilectr[224] + done[1]

    hipMemsetAsync(ctrs, 0, 225 * sizeof(int), stream);

    // 1) deg-GEMM (blocks 0..223) + one-shot pool (blocks 224..65759)
    pool_deggemm_kernel<<<NBLK_DGEMM + NBLK_POOL, 256, 0, stream>>>(x, degraded, w_fusion,
                                                                   fused, pact2);

    // 2) K-split main GEMM + winner epilogue + last-winner finalize: grid (8,28,2)
    gemm_gate_kernel<<<dim3(8, 28, 2), 256, 0, stream>>>(fused, w_fusion, pact2,
                                                         b_fusion, w_gate, pactz, part,
                                                         ctrs, ctrs + 224, out);
}

// Round 12
// 241.695 us; speedup vs baseline: 1.2210x; 1.2210x over previous
//
#include <hip/hip_runtime.h>
#include <math.h>

#define D_X      1024
#define D_TEXT   768
#define FDIM     1792
#define BATCH    256
#define M_EXP    16
#define HW_TOT   1024   // 32*32

// Output layout (flat f32): gates[4096] | moe_loss[1] | probs[4096] | top_idx[512]
#define OUT_GATES 0
#define OUT_LOSS  4096
#define OUT_PROBS 4097
#define OUT_IDX   8193

#define NBLK_DGEMM 224
#define NBLK_POOL  (BATCH * D_X / 8)   // 32768: one wave per TWO rows

// ---------------------------------------------------------------------------
// Kernel 1:
//   blocks [0, 224):      deg-GEMM  pact2 = degraded @ W[1024:, :]  (proven)
//   blocks [224, 32992):  one-shot mean-pool, one wave per 2 rows (8 float4
//                         in flight per wave — R2-proven inner loop)
// ---------------------------------------------------------------------------
__global__ __launch_bounds__(256) void pool_deggemm_kernel(const float* __restrict__ x,
                                                           const float* __restrict__ deg,
                                                           const float* __restrict__ W,
                                                           float* __restrict__ fused,
                                                           float* __restrict__ pact2) {
    __shared__ float As1[32][33];   // deg tile, transposed [k][m]
    __shared__ float Ws1[32][64];   // W tile [k][n]

    const int bid = blockIdx.x;
    const int tid = threadIdx.x;

    if (bid >= NBLK_DGEMM) {
        // ---- pool path: one wave per 2 consecutive (b,c) rows ----
        const int gtid = (bid - NBLK_DGEMM) * 256 + tid;
        const int wv   = gtid >> 6;            // 0 .. 32767
        const int lane = gtid & 63;
        const int r2   = wv * 2;               // rows r2, r2+1 (contiguous memory)
        const float4* x0 = reinterpret_cast<const float4*>(x + (size_t)r2 * HW_TOT);
        float4 v0[4], v1[4];
#pragma unroll
        for (int k = 0; k < 4; ++k) v0[k] = x0[k * 64 + lane];
#pragma unroll
        for (int k = 0; k < 4; ++k) v1[k] = x0[256 + k * 64 + lane];
        float s0 = 0.0f, s1 = 0.0f;
#pragma unroll
        for (int k = 0; k < 4; ++k) {
            s0 += v0[k].x + v0[k].y + v0[k].z + v0[k].w;
            s1 += v1[k].x + v1[k].y + v1[k].z + v1[k].w;
        }
#pragma unroll
        for (int off = 32; off > 0; off >>= 1) {
            s0 += __shfl_xor(s0, off, 64);
            s1 += __shfl_xor(s1, off, 64);
        }
        if (lane == 0) {
            float2 st;
            st.x = s0 * (1.0f / 1024.0f);
            st.y = s1 * (1.0f / 1024.0f);
            *reinterpret_cast<float2*>(&fused[r2]) = st;   // fused dense (256,1024)
        }
        return;
    }

    // ---- deg-GEMM path: 32m x 64n tile, BK=32, 24 iters (verbatim) ----
    const int mb = bid / 28;
    const int nb = bid % 28;
    const int m0 = mb * 32;
    const int n0 = nb * 64;

    const int tx = tid & 15;        // n-groups of 4
    const int ty = tid >> 4;        // m-groups of 2

    const int ar  = tid >> 3;       // A row 0..31
    const int ak4 = (tid & 7) * 4;  // A k-col
    const int wk  = tid >> 4;       // W k-row (+16 for second)
    const int wc4 = (tid & 15) * 4; // W n-col

    float acc[2][4] = {};

    for (int k0 = 0; k0 < D_TEXT; k0 += 32) {
        __syncthreads();
        {
            const float4 a = *reinterpret_cast<const float4*>(
                deg + (size_t)(m0 + ar) * D_TEXT + k0 + ak4);
            As1[ak4 + 0][ar] = a.x; As1[ak4 + 1][ar] = a.y;
            As1[ak4 + 2][ar] = a.z; As1[ak4 + 3][ar] = a.w;
            *reinterpret_cast<float4*>(&Ws1[wk][wc4]) =
                *reinterpret_cast<const float4*>(W + (size_t)(D_X + k0 + wk) * FDIM + n0 + wc4);
            *reinterpret_cast<float4*>(&Ws1[wk + 16][wc4]) =
                *reinterpret_cast<const float4*>(W + (size_t)(D_X + k0 + wk + 16) * FDIM + n0 + wc4);
        }
        __syncthreads();
#pragma unroll
        for (int kk = 0; kk < 32; ++kk) {
            const float2 a = *reinterpret_cast<const float2*>(&As1[kk][ty * 2]);
            const float4 w = *reinterpret_cast<const float4*>(&Ws1[kk][tx * 4]);
            acc[0][0] = fmaf(a.x, w.x, acc[0][0]);
            acc[0][1] = fmaf(a.x, w.y, acc[0][1]);
            acc[0][2] = fmaf(a.x, w.z, acc[0][2]);
            acc[0][3] = fmaf(a.x, w.w, acc[0][3]);
            acc[1][0] = fmaf(a.y, w.x, acc[1][0]);
            acc[1][1] = fmaf(a.y, w.y, acc[1][1]);
            acc[1][2] = fmaf(a.y, w.z, acc[1][2]);
            acc[1][3] = fmaf(a.y, w.w, acc[1][3]);
        }
    }

#pragma unroll
    for (int i = 0; i < 2; ++i) {
        float4 v;
        v.x = acc[i][0]; v.y = acc[i][1]; v.z = acc[i][2]; v.w = acc[i][3];
        *reinterpret_cast<float4*>(pact2 + (size_t)(m0 + ty * 2 + i) * FDIM + n0 + tx * 4) = v;
    }
}

// ---------------------------------------------------------------------------
// Kernel 2 (verbatim R9 champion): main GEMM (K in [0,1024), wave-K-split)
// + bias + GELU + gate partials + last-block finalize.
// ---------------------------------------------------------------------------
#define BM 32
#define BN 64
#define BK 64
#define KDIM D_X            // 1024
#define NITER (KDIM / BK)   // 16
#define ASTR 36             // padded A row stride (16B-aligned rows)

#define AS(buf, k, m) As[(buf) * 2304 + (k) * ASTR + (m)]
#define WS(buf, k, n) Ws[(buf) * 4096 + (k) * 64 + (n)]
#define PACC(w, m, n) smem[(w) * 2048 + (m) * 64 + (n)]
#define ACTS(m, n)    smem[8192 + (m) * 65 + (n)]
#define WGS(n, e)     smem[10272 + (n) * M_EXP + (e)]

#define LOADA(k0)                                                                            \
    pa0 = *reinterpret_cast<const float4*>(A + (size_t)(m0 + ar) * KDIM + (k0) + ak4);       \
    pa1 = *reinterpret_cast<const float4*>(A + (size_t)(m0 + ar + 16) * KDIM + (k0) + ak4);

#define LOADW(k0)                                                                            \
    pw0 = *reinterpret_cast<const float4*>(W + (size_t)((k0) + wr0) * FDIM + n0 + wc4);      \
    pw1 = *reinterpret_cast<const float4*>(W + (size_t)((k0) + wr0 + 16) * FDIM + n0 + wc4); \
    pw2 = *reinterpret_cast<const float4*>(W + (size_t)((k0) + wr0 + 32) * FDIM + n0 + wc4); \
    pw3 = *reinterpret_cast<const float4*>(W + (size_t)((k0) + wr0 + 48) * FDIM + n0 + wc4);

#define STOREA(buf)                                                                          \
    AS(buf, ak4 + 0, ar) = pa0.x; AS(buf, ak4 + 1, ar) = pa0.y;                              \
    AS(buf, ak4 + 2, ar) = pa0.z; AS(buf, ak4 + 3, ar) = pa0.w;                              \
    AS(buf, ak4 + 0, ar + 16) = pa1.x; AS(buf, ak4 + 1, ar + 16) = pa1.y;                    \
    AS(buf, ak4 + 2, ar + 16) = pa1.z; AS(buf, ak4 + 3, ar + 16) = pa1.w;

#define STOREW(buf)                                                                          \
    *reinterpret_cast<float4*>(&WS(buf, wr0, wc4))      = pw0;                               \
    *reinterpret_cast<float4*>(&WS(buf, wr0 + 16, wc4)) = pw1;                               \
    *reinterpret_cast<float4*>(&WS(buf, wr0 + 32, wc4)) = pw2;                               \
    *reinterpret_cast<float4*>(&WS(buf, wr0 + 48, wc4)) = pw3;

__global__ __launch_bounds__(256) void gemm_gate_kernel(const float* __restrict__ A,
                                                        const float* __restrict__ W,
                                                        const float* __restrict__ pact2,
                                                        const float* __restrict__ bias,
                                                        const float* __restrict__ wg,
                                                        float* __restrict__ part,
                                                        int* __restrict__ done,
                                                        float* __restrict__ out) {
    __shared__ float smem[12800];
    __shared__ int isLast;
    float* As = smem;
    float* Ws = smem + 4608;

    const int tid = threadIdx.x;
    const int m0 = blockIdx.x * BM;
    const int n0 = blockIdx.y * BN;

    const int ar  = tid >> 4;             // A rows ar, ar+16
    const int ak4 = (tid & 15) * 4;
    const int wr0 = tid >> 4;             // W k-rows wr0,+16,+32,+48
    const int wc4 = (tid & 15) * 4;

    // consumption map: wave-K-split, per-lane 4m x 8n
    const int wv   = tid >> 6;            // wave 0..3 -> kk in [wv*16, wv*16+16)
    const int lane = tid & 63;
    const int mg   = lane >> 3;           // m = mg*4 + i
    const int ng   = lane & 7;            // n = ng*8 + j

    float4 pa0, pa1, pw0, pw1, pw2, pw3;

    LOADA(0); LOADW(0);
    STOREA(0); STOREW(0);
    LOADA(BK); LOADW(BK);
    __syncthreads();

    float acc[4][8] = {};
    int cur = 0;

    for (int t = 0; t < NITER; ++t) {
#pragma unroll
        for (int s = 0; s < 16; ++s) {
            const int kk = wv * 16 + s;
            const float4 a  = *reinterpret_cast<const float4*>(&AS(cur, kk, mg * 4));
            const float4 w0 = *reinterpret_cast<const float4*>(&WS(cur, kk, ng * 8));
            const float4 w1 = *reinterpret_cast<const float4*>(&WS(cur, kk, ng * 8 + 4));
            const float av[4] = {a.x, a.y, a.z, a.w};
            const float wvv[8] = {w0.x, w0.y, w0.z, w0.w, w1.x, w1.y, w1.z, w1.w};
#pragma unroll
            for (int i = 0; i < 4; ++i)
#pragma unroll
                for (int j = 0; j < 8; ++j)
                    acc[i][j] = fmaf(av[i], wvv[j], acc[i][j]);
        }
        if (t < NITER - 1) {
            const int nxt = cur ^ 1;
            STOREA(nxt); STOREW(nxt);
            if (t < NITER - 2) {
                const int k0 = (t + 2) * BK;
                LOADA(k0); LOADW(k0);
            }
            __syncthreads();
            cur = nxt;
        }
    }

    // ---- phase B: wave-partial reduce + epilogue (smem re-purposed) ----
    __syncthreads();   // all consumption done before overwriting As/Ws

#pragma unroll
    for (int i = 0; i < 4; ++i) {
        float4 v0, v1;
        v0.x = acc[i][0]; v0.y = acc[i][1]; v0.z = acc[i][2]; v0.w = acc[i][3];
        v1.x = acc[i][4]; v1.y = acc[i][5]; v1.z = acc[i][6]; v1.w = acc[i][7];
        *reinterpret_cast<float4*>(&PACC(wv, mg * 4 + i, ng * 8))     = v0;
        *reinterpret_cast<float4*>(&PACC(wv, mg * 4 + i, ng * 8 + 4)) = v1;
    }
    {
        const int r  = tid >> 2;
        const int c4 = (tid & 3) * 4;
        *reinterpret_cast<float4*>(&WGS(r, c4)) =
            *reinterpret_cast<const float4*>(wg + (size_t)(n0 + r) * M_EXP + c4);
    }
    __syncthreads();

    // reduce 4 wave-partials (fixed order) + pact2 + bias, exact GELU -> actS
    {
        const int m   = tid >> 3;            // 0..31
        const int nb8 = (tid & 7) * 8;       // 0..56
#pragma unroll
        for (int h = 0; h < 2; ++h) {
            const int n = nb8 + h * 4;
            const float4 p  = *reinterpret_cast<const float4*>(
                pact2 + (size_t)(m0 + m) * FDIM + n0 + n);
            const float4 bb = *reinterpret_cast<const float4*>(bias + n0 + n);
            const float pv[4] = {p.x, p.y, p.z, p.w};
            const float bv[4] = {bb.x, bb.y, bb.z, bb.w};
#pragma unroll
            for (int j = 0; j < 4; ++j) {
                const float v = ((PACC(0, m, n + j) + PACC(1, m, n + j))
                               + (PACC(2, m, n + j) + PACC(3, m, n + j)))
                               + pv[j] + bv[j];
                ACTS(m, n + j) = v * 0.5f * (1.0f + erff(v * 0.70710678118654752440f));
            }
        }
    }
    __syncthreads();

    // gate partials: 32 rows x 16 experts, 2 per thread
    const int pm = tid >> 3;
    const int pe = (tid & 7) * 2;
    float s0 = 0.0f, s1 = 0.0f;
#pragma unroll
    for (int n = 0; n < BN; ++n) {
        const float a = ACTS(pm, n);
        s0 = fmaf(a, WGS(n, pe), s0);
        s1 = fmaf(a, WGS(n, pe + 1), s1);
    }
    float* pr = part + ((size_t)blockIdx.y * BATCH + m0 + pm) * M_EXP + pe;
    pr[0] = s0;
    pr[1] = s1;

    // ---- last-block finalize (no polling; single ACQ_REL RMW per block) ----
    __threadfence();
    __syncthreads();
    if (tid == 0) {
        const int prev = __hip_atomic_fetch_add(done, 1, __ATOMIC_ACQ_REL,
                                                __HIP_MEMORY_SCOPE_AGENT);
        isLast = (prev == 8 * 28 - 1);
    }
    __syncthreads();
    if (!isLast) return;

    {
        const int b = tid;    // 256 threads = 256 rows
        float l[M_EXP];
#pragma unroll
        for (int m = 0; m < M_EXP; ++m) l[m] = 0.0f;
        for (int nb2 = 0; nb2 < FDIM / BN; ++nb2) {
            const float4* prr = reinterpret_cast<const float4*>(
                part + ((size_t)nb2 * BATCH + b) * M_EXP);
#pragma unroll
            for (int q = 0; q < 4; ++q) {
                const float4 v = prr[q];
                l[q * 4 + 0] += v.x;
                l[q * 4 + 1] += v.y;
                l[q * 4 + 2] += v.z;
                l[q * 4 + 3] += v.w;
            }
        }
        float mx = l[0];
#pragma unroll
        for (int m = 1; m < M_EXP; ++m) mx = fmaxf(mx, l[m]);
        float e[M_EXP], s = 0.0f;
#pragma unroll
        for (int m = 0; m < M_EXP; ++m) { e[m] = expf(l[m] - mx); s += e[m]; }
        const float inv = 1.0f / s;
#pragma unroll
        for (int m = 0; m < M_EXP; ++m) out[OUT_PROBS + b * M_EXP + m] = e[m] * inv;

        int i0 = 0; float v0 = l[0];
#pragma unroll
        for (int m = 1; m < M_EXP; ++m) if (l[m] > v0) { v0 = l[m]; i0 = m; }
        int i1 = -1; float v1 = -INFINITY;
#pragma unroll
        for (int m = 0; m < M_EXP; ++m) if (m != i0 && l[m] > v1) { v1 = l[m]; i1 = m; }

        const float t = expf(v1 - v0);
        const float g0 = 1.0f / (1.0f + t);
        const float g1 = t * g0;
#pragma unroll
        for (int m = 0; m < M_EXP; ++m) out[OUT_GATES + b * M_EXP + m] = 0.0f;
        out[OUT_GATES + b * M_EXP + i0] = g0;
        out[OUT_GATES + b * M_EXP + i1] = g1;
        out[OUT_IDX + b * 2 + 0] = (float)i0;
        out[OUT_IDX + b * 2 + 1] = (float)i1;
        if (b == 0) out[OUT_LOSS] = 0.0f;
    }
}

// ---------------------------------------------------------------------------
extern "C" void kernel_launch(void* const* d_in, const int* in_sizes, int n_in,
                              void* d_out, int out_size, void* d_ws, size_t ws_size,
                              hipStream_t stream) {
    const float* x        = (const float*)d_in[0];
    const float* degraded = (const float*)d_in[1];
    const float* w_fusion = (const float*)d_in[2];
    const float* b_fusion = (const float*)d_in[3];
    const float* w_gate   = (const float*)d_in[4];
    float* out = (float*)d_out;

    float* fused = (float*)d_ws;                          // 256*1024 f32 (dense)
    float* pact2 = fused + (size_t)BATCH * D_X;           // 256*1792 f32
    float* part  = pact2 + (size_t)BATCH * FDIM;          // 28*256*16 f32
    int*   done  = (int*)(part + (size_t)28 * BATCH * M_EXP);

    hipMemsetAsync(done, 0, sizeof(int), stream);

    // 1) deg-GEMM (blocks 0..223) + one-shot pool, 2 rows/wave (blocks 224..32991)
    pool_deggemm_kernel<<<NBLK_DGEMM + NBLK_POOL, 256, 0, stream>>>(x, degraded, w_fusion,
                                                                   fused, pact2);

    // 2) main GEMM + gelu + gate partials + last-block finalize: grid (8, 28)
    gemm_gate_kernel<<<dim3(BATCH / BM, FDIM / BN), 256, 0, stream>>>(fused, w_fusion, pact2,
                                                                     b_fusion, w_gate, part,
                                                                     done, out);
}

// Round 13
// 234.015 us; speedup vs baseline: 1.2611x; 1.0328x over previous
//
#include <hip/hip_runtime.h>
#include <math.h>

#define D_X      1024
#define D_TEXT   768
#define FDIM     1792
#define BATCH    256
#define M_EXP    16
#define HW_TOT   1024   // 32*32

// Output layout (flat f32): gates[4096] | moe_loss[1] | probs[4096] | top_idx[512]
#define OUT_GATES 0
#define OUT_LOSS  4096
#define OUT_PROBS 4097
#define OUT_IDX   8193

#define NBLK_DGEMM 224
#define NBLK_POOL  (BATCH * D_X / 4)   // 65536

// ---------------------------------------------------------------------------
// Kernel 1 (champion form, R5/R9):
//   blocks [0, 224):      deg-GEMM  pact2 = degraded @ W[1024:, :]
//                         (no pool dependency -> hidden under the pool)
//   blocks [224, 65760):  one-shot mean-pool, one wave per (b,c) row
// ---------------------------------------------------------------------------
__global__ __launch_bounds__(256) void pool_deggemm_kernel(const float* __restrict__ x,
                                                           const float* __restrict__ deg,
                                                           const float* __restrict__ W,
                                                           float* __restrict__ fused,
                                                           float* __restrict__ pact2) {
    __shared__ float As1[32][33];   // deg tile, transposed [k][m]
    __shared__ float Ws1[32][64];   // W tile [k][n]

    const int bid = blockIdx.x;
    const int tid = threadIdx.x;

    if (bid >= NBLK_DGEMM) {
        // ---- pool path: one wave per (b,c) row of 1024 contiguous floats ----
        const int gtid = (bid - NBLK_DGEMM) * 256 + tid;
        const int row  = gtid >> 6;            // 0 .. 262143
        const int lane = gtid & 63;
        const float4* xr = reinterpret_cast<const float4*>(x + (size_t)row * HW_TOT);
        float s = 0.0f;
#pragma unroll
        for (int k = 0; k < 4; ++k) {
            float4 v = xr[k * 64 + lane];
            s += v.x + v.y + v.z + v.w;
        }
#pragma unroll
        for (int off = 32; off > 0; off >>= 1) s += __shfl_xor(s, off, 64);
        if (lane == 0) fused[row] = s * (1.0f / 1024.0f);   // fused dense (256,1024)
        return;
    }

    // ---- deg-GEMM path: 32m x 64n tile, BK=32, 24 iters ----
    const int mb = bid / 28;
    const int nb = bid % 28;
    const int m0 = mb * 32;
    const int n0 = nb * 64;

    const int tx = tid & 15;        // n-groups of 4
    const int ty = tid >> 4;        // m-groups of 2

    const int ar  = tid >> 3;       // A row 0..31
    const int ak4 = (tid & 7) * 4;  // A k-col
    const int wk  = tid >> 4;       // W k-row (+16 for second)
    const int wc4 = (tid & 15) * 4; // W n-col

    float acc[2][4] = {};

    for (int k0 = 0; k0 < D_TEXT; k0 += 32) {
        __syncthreads();
        {
            const float4 a = *reinterpret_cast<const float4*>(
                deg + (size_t)(m0 + ar) * D_TEXT + k0 + ak4);
            As1[ak4 + 0][ar] = a.x; As1[ak4 + 1][ar] = a.y;
            As1[ak4 + 2][ar] = a.z; As1[ak4 + 3][ar] = a.w;
            *reinterpret_cast<float4*>(&Ws1[wk][wc4]) =
                *reinterpret_cast<const float4*>(W + (size_t)(D_X + k0 + wk) * FDIM + n0 + wc4);
            *reinterpret_cast<float4*>(&Ws1[wk + 16][wc4]) =
                *reinterpret_cast<const float4*>(W + (size_t)(D_X + k0 + wk + 16) * FDIM + n0 + wc4);
        }
        __syncthreads();
#pragma unroll
        for (int kk = 0; kk < 32; ++kk) {
            const float2 a = *reinterpret_cast<const float2*>(&As1[kk][ty * 2]);
            const float4 w = *reinterpret_cast<const float4*>(&Ws1[kk][tx * 4]);
            acc[0][0] = fmaf(a.x, w.x, acc[0][0]);
            acc[0][1] = fmaf(a.x, w.y, acc[0][1]);
            acc[0][2] = fmaf(a.x, w.z, acc[0][2]);
            acc[0][3] = fmaf(a.x, w.w, acc[0][3]);
            acc[1][0] = fmaf(a.y, w.x, acc[1][0]);
            acc[1][1] = fmaf(a.y, w.y, acc[1][1]);
            acc[1][2] = fmaf(a.y, w.z, acc[1][2]);
            acc[1][3] = fmaf(a.y, w.w, acc[1][3]);
        }
    }

#pragma unroll
    for (int i = 0; i < 2; ++i) {
        float4 v;
        v.x = acc[i][0]; v.y = acc[i][1]; v.z = acc[i][2]; v.w = acc[i][3];
        *reinterpret_cast<float4*>(pact2 + (size_t)(m0 + ty * 2 + i) * FDIM + n0 + tx * 4) = v;
    }
}

// ---------------------------------------------------------------------------
// Kernel 2 (champion form, R9): main GEMM (K in [0,1024), wave-K-split)
// + bias + exact GELU + gate partials + last-block finalize.
// ---------------------------------------------------------------------------
#define BM 32
#define BN 64
#define BK 64
#define KDIM D_X            // 1024
#define NITER (KDIM / BK)   // 16
#define ASTR 36             // padded A row stride (16B-aligned rows)

#define AS(buf, k, m) As[(buf) * 2304 + (k) * ASTR + (m)]
#define WS(buf, k, n) Ws[(buf) * 4096 + (k) * 64 + (n)]
#define PACC(w, m, n) smem[(w) * 2048 + (m) * 64 + (n)]
#define ACTS(m, n)    smem[8192 + (m) * 65 + (n)]
#define WGS(n, e)     smem[10272 + (n) * M_EXP + (e)]

#define LOADA(k0)                                                                            \
    pa0 = *reinterpret_cast<const float4*>(A + (size_t)(m0 + ar) * KDIM + (k0) + ak4);       \
    pa1 = *reinterpret_cast<const float4*>(A + (size_t)(m0 + ar + 16) * KDIM + (k0) + ak4);

#define LOADW(k0)                                                                            \
    pw0 = *reinterpret_cast<const float4*>(W + (size_t)((k0) + wr0) * FDIM + n0 + wc4);      \
    pw1 = *reinterpret_cast<const float4*>(W + (size_t)((k0) + wr0 + 16) * FDIM + n0 + wc4); \
    pw2 = *reinterpret_cast<const float4*>(W + (size_t)((k0) + wr0 + 32) * FDIM + n0 + wc4); \
    pw3 = *reinterpret_cast<const float4*>(W + (size_t)((k0) + wr0 + 48) * FDIM + n0 + wc4);

#define STOREA(buf)                                                                          \
    AS(buf, ak4 + 0, ar) = pa0.x; AS(buf, ak4 + 1, ar) = pa0.y;                              \
    AS(buf, ak4 + 2, ar) = pa0.z; AS(buf, ak4 + 3, ar) = pa0.w;                              \
    AS(buf, ak4 + 0, ar + 16) = pa1.x; AS(buf, ak4 + 1, ar + 16) = pa1.y;                    \
    AS(buf, ak4 + 2, ar + 16) = pa1.z; AS(buf, ak4 + 3, ar + 16) = pa1.w;

#define STOREW(buf)                                                                          \
    *reinterpret_cast<float4*>(&WS(buf, wr0, wc4))      = pw0;                               \
    *reinterpret_cast<float4*>(&WS(buf, wr0 + 16, wc4)) = pw1;                               \
    *reinterpret_cast<float4*>(&WS(buf, wr0 + 32, wc4)) = pw2;                               \
    *reinterpret_cast<float4*>(&WS(buf, wr0 + 48, wc4)) = pw3;

__global__ __launch_bounds__(256) void gemm_gate_kernel(const float* __restrict__ A,
                                                        const float* __restrict__ W,
                                                        const float* __restrict__ pact2,
                                                        const float* __restrict__ bias,
                                                        const float* __restrict__ wg,
                                                        float* __restrict__ part,
                                                        int* __restrict__ done,
                                                        float* __restrict__ out) {
    __shared__ float smem[12800];
    __shared__ int isLast;
    float* As = smem;
    float* Ws = smem + 4608;

    const int tid = threadIdx.x;
    const int m0 = blockIdx.x * BM;
    const int n0 = blockIdx.y * BN;

    const int ar  = tid >> 4;             // A rows ar, ar+16
    const int ak4 = (tid & 15) * 4;
    const int wr0 = tid >> 4;             // W k-rows wr0,+16,+32,+48
    const int wc4 = (tid & 15) * 4;

    // consumption map: wave-K-split, per-lane 4m x 8n
    const int wv   = tid >> 6;            // wave 0..3 -> kk in [wv*16, wv*16+16)
    const int lane = tid & 63;
    const int mg   = lane >> 3;           // m = mg*4 + i
    const int ng   = lane & 7;            // n = ng*8 + j

    float4 pa0, pa1, pw0, pw1, pw2, pw3;

    LOADA(0); LOADW(0);
    STOREA(0); STOREW(0);
    LOADA(BK); LOADW(BK);
    __syncthreads();

    float acc[4][8] = {};
    int cur = 0;

    for (int t = 0; t < NITER; ++t) {
#pragma unroll
        for (int s = 0; s < 16; ++s) {
            const int kk = wv * 16 + s;
            const float4 a  = *reinterpret_cast<const float4*>(&AS(cur, kk, mg * 4));
            const float4 w0 = *reinterpret_cast<const float4*>(&WS(cur, kk, ng * 8));
            const float4 w1 = *reinterpret_cast<const float4*>(&WS(cur, kk, ng * 8 + 4));
            const float av[4] = {a.x, a.y, a.z, a.w};
            const float wvv[8] = {w0.x, w0.y, w0.z, w0.w, w1.x, w1.y, w1.z, w1.w};
#pragma unroll
            for (int i = 0; i < 4; ++i)
#pragma unroll
                for (int j = 0; j < 8; ++j)
                    acc[i][j] = fmaf(av[i], wvv[j], acc[i][j]);
        }
        if (t < NITER - 1) {
            const int nxt = cur ^ 1;
            STOREA(nxt); STOREW(nxt);
            if (t < NITER - 2) {
                const int k0 = (t + 2) * BK;
                LOADA(k0); LOADW(k0);
            }
            __syncthreads();
            cur = nxt;
        }
    }

    // ---- phase B: wave-partial reduce + epilogue (smem re-purposed) ----
    __syncthreads();   // all consumption done before overwriting As/Ws

#pragma unroll
    for (int i = 0; i < 4; ++i) {
        float4 v0, v1;
        v0.x = acc[i][0]; v0.y = acc[i][1]; v0.z = acc[i][2]; v0.w = acc[i][3];
        v1.x = acc[i][4]; v1.y = acc[i][5]; v1.z = acc[i][6]; v1.w = acc[i][7];
        *reinterpret_cast<float4*>(&PACC(wv, mg * 4 + i, ng * 8))     = v0;
        *reinterpret_cast<float4*>(&PACC(wv, mg * 4 + i, ng * 8 + 4)) = v1;
    }
    {
        const int r  = tid >> 2;
        const int c4 = (tid & 3) * 4;
        *reinterpret_cast<float4*>(&WGS(r, c4)) =
            *reinterpret_cast<const float4*>(wg + (size_t)(n0 + r) * M_EXP + c4);
    }
    __syncthreads();

    // reduce 4 wave-partials (fixed order) + pact2 + bias, exact GELU -> actS
    {
        const int m   = tid >> 3;            // 0..31
        const int nb8 = (tid & 7) * 8;       // 0..56
#pragma unroll
        for (int h = 0; h < 2; ++h) {
            const int n = nb8 + h * 4;
            const float4 p  = *reinterpret_cast<const float4*>(
                pact2 + (size_t)(m0 + m) * FDIM + n0 + n);
            const float4 bb = *reinterpret_cast<const float4*>(bias + n0 + n);
            const float pv[4] = {p.x, p.y, p.z, p.w};
            const float bv[4] = {bb.x, bb.y, bb.z, bb.w};
#pragma unroll
            for (int j = 0; j < 4; ++j) {
                const float v = ((PACC(0, m, n + j) + PACC(1, m, n + j))
                               + (PACC(2, m, n + j) + PACC(3, m, n + j)))
                               + pv[j] + bv[j];
                ACTS(m, n + j) = v * 0.5f * (1.0f + erff(v * 0.70710678118654752440f));
            }
        }
    }
    __syncthreads();

    // gate partials: 32 rows x 16 experts, 2 per thread
    const int pm = tid >> 3;
    const int pe = (tid & 7) * 2;
    float s0 = 0.0f, s1 = 0.0f;
#pragma unroll
    for (int n = 0; n < BN; ++n) {
        const float a = ACTS(pm, n);
        s0 = fmaf(a, WGS(n, pe), s0);
        s1 = fmaf(a, WGS(n, pe + 1), s1);
    }
    float* pr = part + ((size_t)blockIdx.y * BATCH + m0 + pm) * M_EXP + pe;
    pr[0] = s0;
    pr[1] = s1;

    // ---- last-block finalize (no polling; single ACQ_REL RMW per block) ----
    __threadfence();
    __syncthreads();
    if (tid == 0) {
        const int prev = __hip_atomic_fetch_add(done, 1, __ATOMIC_ACQ_REL,
                                                __HIP_MEMORY_SCOPE_AGENT);
        isLast = (prev == 8 * 28 - 1);
    }
    __syncthreads();
    if (!isLast) return;

    {
        const int b = tid;    // 256 threads = 256 rows
        float l[M_EXP];
#pragma unroll
        for (int m = 0; m < M_EXP; ++m) l[m] = 0.0f;
        for (int nb2 = 0; nb2 < FDIM / BN; ++nb2) {
            const float4* prr = reinterpret_cast<const float4*>(
                part + ((size_t)nb2 * BATCH + b) * M_EXP);
#pragma unroll
            for (int q = 0; q < 4; ++q) {
                const float4 v = prr[q];
                l[q * 4 + 0] += v.x;
                l[q * 4 + 1] += v.y;
                l[q * 4 + 2] += v.z;
                l[q * 4 + 3] += v.w;
            }
        }
        float mx = l[0];
#pragma unroll
        for (int m = 1; m < M_EXP; ++m) mx = fmaxf(mx, l[m]);
        float e[M_EXP], s = 0.0f;
#pragma unroll
        for (int m = 0; m < M_EXP; ++m) { e[m] = expf(l[m] - mx); s += e[m]; }
        const float inv = 1.0f / s;
#pragma unroll
        for (int m = 0; m < M_EXP; ++m) out[OUT_PROBS + b * M_EXP + m] = e[m] * inv;

        int i0 = 0; float v0 = l[0];
#pragma unroll
        for (int m = 1; m < M_EXP; ++m) if (l[m] > v0) { v0 = l[m]; i0 = m; }
        int i1 = -1; float v1 = -INFINITY;
#pragma unroll
        for (int m = 0; m < M_EXP; ++m) if (m != i0 && l[m] > v1) { v1 = l[m]; i1 = m; }

        const float t = expf(v1 - v0);
        const float g0 = 1.0f / (1.0f + t);
        const float g1 = t * g0;
#pragma unroll
        for (int m = 0; m < M_EXP; ++m) out[OUT_GATES + b * M_EXP + m] = 0.0f;
        out[OUT_GATES + b * M_EXP + i0] = g0;
        out[OUT_GATES + b * M_EXP + i1] = g1;
        out[OUT_IDX + b * 2 + 0] = (float)i0;
        out[OUT_IDX + b * 2 + 1] = (float)i1;
        if (b == 0) out[OUT_LOSS] = 0.0f;
    }
}

// ---------------------------------------------------------------------------
extern "C" void kernel_launch(void* const* d_in, const int* in_sizes, int n_in,
                              void* d_out, int out_size, void* d_ws, size_t ws_size,
                              hipStream_t stream) {
    const float* x        = (const float*)d_in[0];
    const float* degraded = (const float*)d_in[1];
    const float* w_fusion = (const float*)d_in[2];
    const float* b_fusion = (const float*)d_in[3];
    const float* w_gate   = (const float*)d_in[4];
    float* out = (float*)d_out;

    float* fused = (float*)d_ws;                          // 256*1024 f32 (dense)
    float* pact2 = fused + (size_t)BATCH * D_X;           // 256*1792 f32
    float* part  = pact2 + (size_t)BATCH * FDIM;          // 28*256*16 f32
    int*   done  = (int*)(part + (size_t)28 * BATCH * M_EXP);

    hipMemsetAsync(done, 0, sizeof(int), stream);

    // 1) deg-GEMM (blocks 0..223, hidden under pool) + one-shot pool
    pool_deggemm_kernel<<<NBLK_DGEMM + NBLK_POOL, 256, 0, stream>>>(x, degraded, w_fusion,
                                                                   fused, pact2);

    // 2) main GEMM + gelu + gate partials + last-block finalize: grid (8, 28)
    gemm_gate_kernel<<<dim3(BATCH / BM, FDIM / BN), 256, 0, stream>>>(fused, w_fusion, pact2,
                                                                     b_fusion, w_gate, part,
                                                                     done, out);
}